// Round 1
// baseline (1588.861 us; speedup 1.0000x reference)
//
#include <hip/hip_runtime.h>
#include <hip/hip_bf16.h>

#define TT 4096
#define SS 4096
#define DD 128
#define NB 64          // bands of 64 rows, one wave each
#define HUGEV 1e30f

// ---------------- init: zero progress flags (must happen every launch: graph replay) ---
__global__ __launch_bounds__(64) void dtw_init(int* __restrict__ progress) {
  if (threadIdx.x < NB) progress[threadIdx.x] = 0;
}

// ---------------- row norms ----------------
__global__ __launch_bounds__(256) void dtw_norms(const float* __restrict__ ref,
                                                 const float* __restrict__ tgt,
                                                 float* __restrict__ r2,
                                                 float* __restrict__ t2) {
  int i = blockIdx.x * 256 + threadIdx.x;
  const float* p = (i < TT) ? (ref + (size_t)i * DD) : (tgt + (size_t)(i - TT) * DD);
  float s = 0.f;
#pragma unroll
  for (int k = 0; k < DD; k += 4) {
    float4 v = *(const float4*)(p + k);
    s = fmaf(v.x, v.x, s); s = fmaf(v.y, v.y, s);
    s = fmaf(v.z, v.z, s); s = fmaf(v.w, v.w, s);
  }
  if (i < TT) r2[i] = s; else t2[i - TT] = s;
}

// ---------------- dist = sqrt(r2 + t2 - 2*ref.tgt^T), stored bf16 ----------------
// 64x64 tile per 256-thread block, fp32 VALU, LDS-staged, K-chunk = 32.
__global__ __launch_bounds__(256) void dtw_dist(const float* __restrict__ ref,
                                                const float* __restrict__ tgt,
                                                const float* __restrict__ r2,
                                                const float* __restrict__ t2,
                                                unsigned short* __restrict__ dist) {
  __shared__ float As[32][68];   // [k][m], pad 68 (mult of 4 -> float4-aligned rows)
  __shared__ float Bs[32][68];   // [k][n]
  const int tid = threadIdx.x;
  const int tx = tid & 15, ty = tid >> 4;
  const int i0 = blockIdx.y * 64, j0 = blockIdx.x * 64;
  const int lrow = tid >> 3;            // 0..31
  const int lk = (tid & 7) << 2;        // 0,4,...,28
  const float* ap = ref + (size_t)(i0 + lrow) * DD + lk;
  const float* bp = tgt + (size_t)(j0 + lrow) * DD + lk;
  float acc[4][4] = {};
  for (int k0 = 0; k0 < DD; k0 += 32) {
    float4 a0 = *(const float4*)(ap + k0);
    float4 a1 = *(const float4*)(ap + k0 + 32 * DD);
    float4 b0 = *(const float4*)(bp + k0);
    float4 b1 = *(const float4*)(bp + k0 + 32 * DD);
    __syncthreads();
    As[lk + 0][lrow] = a0.x; As[lk + 1][lrow] = a0.y; As[lk + 2][lrow] = a0.z; As[lk + 3][lrow] = a0.w;
    As[lk + 0][lrow + 32] = a1.x; As[lk + 1][lrow + 32] = a1.y; As[lk + 2][lrow + 32] = a1.z; As[lk + 3][lrow + 32] = a1.w;
    Bs[lk + 0][lrow] = b0.x; Bs[lk + 1][lrow] = b0.y; Bs[lk + 2][lrow] = b0.z; Bs[lk + 3][lrow] = b0.w;
    Bs[lk + 0][lrow + 32] = b1.x; Bs[lk + 1][lrow + 32] = b1.y; Bs[lk + 2][lrow + 32] = b1.z; Bs[lk + 3][lrow + 32] = b1.w;
    __syncthreads();
#pragma unroll
    for (int k = 0; k < 32; ++k) {
      float4 av = *(const float4*)&As[k][ty << 2];
      float4 bv = *(const float4*)&Bs[k][tx << 2];
      float aa[4] = {av.x, av.y, av.z, av.w};
      float bb[4] = {bv.x, bv.y, bv.z, bv.w};
#pragma unroll
      for (int r = 0; r < 4; ++r)
#pragma unroll
        for (int c = 0; c < 4; ++c) acc[r][c] = fmaf(aa[r], bb[c], acc[r][c]);
    }
  }
#pragma unroll
  for (int r = 0; r < 4; ++r) {
    int i = i0 + (ty << 2) + r;
    float ri = r2[i];
    unsigned short oo[4];
#pragma unroll
    for (int c = 0; c < 4; ++c) {
      int j = j0 + (tx << 2) + c;
      float d2 = ri + t2[j] - 2.0f * acc[r][c];
      float dd = sqrtf(fmaxf(d2, 0.f));
      unsigned bits = __float_as_uint(dd);
      oo[c] = (unsigned short)((bits + 0x7FFFu + ((bits >> 16) & 1u)) >> 16);  // RTNE bf16
    }
    ushort4 ov; ov.x = oo[0]; ov.y = oo[1]; ov.z = oo[2]; ov.w = oo[3];
    *reinterpret_cast<ushort4*>(dist + (size_t)i * SS + j0 + (tx << 2)) = ov;
  }
}

// ---------------- banded wavefront DP ----------------
// Block b = band rows [64b, 64b+64). Lane l owns row 64b+l; at step t it computes
// column t-l. up comes from lane l-1 via shuffle (or from brow[b-1] for lane 0),
// upleft is last step's up, left is the lane's own register.
__global__ __launch_bounds__(64) void dtw_dp(const unsigned short* __restrict__ dist,
                                             float* __restrict__ brow,      // [NB][SS]
                                             int* __restrict__ progress,    // [NB]
                                             float* __restrict__ out) {
  const int b = blockIdx.x;
  const int lane = threadIdx.x;
  __shared__ float upb[64];      // boundary row chunk from band b-1
  __shared__ float botb[64];     // bottom-row values being accumulated (by lane 63)
  const unsigned short* rowp = dist + (size_t)(b * 64 + lane) * SS;

  float a = HUGEV;                                       // acc[row][col-1] (left)
  float upleft = (b == 0 && lane == 0) ? 0.f : HUGEV;    // virtual acc[-1][-1]=0 seed
  unsigned q[16];                                        // prefetch queue, 16 steps deep
#pragma unroll
  for (int s = 0; s < 16; ++s) {
    int c = s - lane;
    q[s] = 0u;
    if (c >= 0) q[s] = rowp[c];
  }

  const int TB = (SS + 64) / 16;   // 260 blocks of 16 steps; t in [0, 4160)
  for (int tb = 0; tb < TB; ++tb) {
    const int t0 = tb * 16;
    // chunk begin: wait for producer + load boundary row chunk
    if ((tb & 3) == 0 && t0 < SS) {
      if (b > 0) {
        const int want = (t0 >> 6) + 1;
        while (__hip_atomic_load(progress + (b - 1), __ATOMIC_ACQUIRE,
                                 __HIP_MEMORY_SCOPE_AGENT) < want) {
          __builtin_amdgcn_s_sleep(1);
        }
        upb[lane] = brow[(size_t)(b - 1) * SS + t0 + lane];
      }
      __syncthreads();
    }
#pragma unroll
    for (int s = 0; s < 16; ++s) {
      const int t = t0 + s;
      const int col = t - lane;
      float bup = HUGEV;
      if (b > 0 && t < SS) bup = upb[t & 63];
      float sh = __shfl_up(a, 1, 64);
      float up = (lane == 0) ? bup : sh;
      float d = __uint_as_float(q[s] << 16);
      float na = d + fminf(fminf(up, upleft), a);
      bool valid = (col >= 0) && (col < SS);
      a = valid ? na : a;
      upleft = up;
      if (lane == 63 && valid) botb[col & 63] = a;
      // prefetch col (t+16-lane) into slot s (consumed 16 steps from now)
      int pc = t + 16 - lane;
      pc = pc < 0 ? 0 : pc;
      pc = pc < SS ? pc : (SS - 1);   // clamped; garbage values are masked at use
      q[s] = rowp[pc];
      // chunk end: lane63 just finished col == cid*64+63  (t % 64 == 62)
      if ((s == 14) && ((tb & 3) == 3) && t >= 126) {
        __syncthreads();
        const int cid = (t - 126) >> 6;
        brow[(size_t)b * SS + cid * 64 + lane] = botb[lane];
        __threadfence();
        if (lane == 0)
          __hip_atomic_store(progress + b, cid + 1, __ATOMIC_RELEASE,
                             __HIP_MEMORY_SCOPE_AGENT);
      }
    }
  }
  if (b == NB - 1 && lane == 63) out[0] = a;   // acc[TT-1][SS-1]
}

extern "C" void kernel_launch(void* const* d_in, const int* in_sizes, int n_in,
                              void* d_out, int out_size, void* d_ws, size_t ws_size,
                              hipStream_t stream) {
  const float* ref = (const float*)d_in[0];
  const float* tgt = (const float*)d_in[1];
  float* out = (float*)d_out;
  char* ws = (char*)d_ws;
  // ws layout: dist bf16 [TT*SS] (32MiB) | brow f32 [NB*SS] (1MiB) | progress (1KiB) | r2 | t2
  unsigned short* dist = (unsigned short*)ws;
  size_t off = (size_t)TT * SS * 2;
  float* brow = (float*)(ws + off);      off += (size_t)NB * SS * 4;
  int* progress = (int*)(ws + off);      off += 1024;
  float* r2 = (float*)(ws + off);        off += (size_t)TT * 4;
  float* t2 = (float*)(ws + off);

  dtw_init<<<1, 64, 0, stream>>>(progress);
  dtw_norms<<<(TT + SS) / 256, 256, 0, stream>>>(ref, tgt, r2, t2);
  dtw_dist<<<dim3(SS / 64, TT / 64), 256, 0, stream>>>(ref, tgt, r2, t2, dist);
  dtw_dp<<<NB, 64, 0, stream>>>(dist, brow, progress, out);
}

// Round 2
// 968.297 us; speedup vs baseline: 1.6409x; 1.6409x over previous
//
#include <hip/hip_runtime.h>
#include <hip/hip_bf16.h>

#define TT 4096
#define SS 4096
#define DD 128
#define HUGEV 1e30f

#define RR 8                    // rows per lane
#define KK 8                    // cols per super-step
#define BH (64 * RR)            // band height = 512
#define NBANDS (TT / BH)        // 8
#define NCHUNK (SS / KK)        // 512 chunks per row-strip
#define NG ((NCHUNK + 63 + 7) / 8)  // 72 groups of 8 super-steps (575 -> 576 steps)

// ---------------- init: zero progress flags (graph replay!) ----------------
__global__ __launch_bounds__(64) void dtw_init(int* __restrict__ progress) {
  progress[threadIdx.x] = 0;
}

// ---------------- row norms ----------------
__global__ __launch_bounds__(256) void dtw_norms(const float* __restrict__ ref,
                                                 const float* __restrict__ tgt,
                                                 float* __restrict__ r2,
                                                 float* __restrict__ t2) {
  int i = blockIdx.x * 256 + threadIdx.x;
  const float* p = (i < TT) ? (ref + (size_t)i * DD) : (tgt + (size_t)(i - TT) * DD);
  float s = 0.f;
#pragma unroll
  for (int k = 0; k < DD; k += 4) {
    float4 v = *(const float4*)(p + k);
    s = fmaf(v.x, v.x, s); s = fmaf(v.y, v.y, s);
    s = fmaf(v.z, v.z, s); s = fmaf(v.w, v.w, s);
  }
  if (i < TT) r2[i] = s; else t2[i - TT] = s;
}

// ---------------- dist = sqrt(r2 + t2 - 2*ref.tgt^T), stored bf16 ----------------
__global__ __launch_bounds__(256) void dtw_dist(const float* __restrict__ ref,
                                                const float* __restrict__ tgt,
                                                const float* __restrict__ r2,
                                                const float* __restrict__ t2,
                                                unsigned short* __restrict__ dist) {
  __shared__ float As[32][68];
  __shared__ float Bs[32][68];
  const int tid = threadIdx.x;
  const int tx = tid & 15, ty = tid >> 4;
  const int i0 = blockIdx.y * 64, j0 = blockIdx.x * 64;
  const int lrow = tid >> 3;
  const int lk = (tid & 7) << 2;
  const float* ap = ref + (size_t)(i0 + lrow) * DD + lk;
  const float* bp = tgt + (size_t)(j0 + lrow) * DD + lk;
  float acc[4][4] = {};
  for (int k0 = 0; k0 < DD; k0 += 32) {
    float4 a0 = *(const float4*)(ap + k0);
    float4 a1 = *(const float4*)(ap + k0 + 32 * DD);
    float4 b0 = *(const float4*)(bp + k0);
    float4 b1 = *(const float4*)(bp + k0 + 32 * DD);
    __syncthreads();
    As[lk + 0][lrow] = a0.x; As[lk + 1][lrow] = a0.y; As[lk + 2][lrow] = a0.z; As[lk + 3][lrow] = a0.w;
    As[lk + 0][lrow + 32] = a1.x; As[lk + 1][lrow + 32] = a1.y; As[lk + 2][lrow + 32] = a1.z; As[lk + 3][lrow + 32] = a1.w;
    Bs[lk + 0][lrow] = b0.x; Bs[lk + 1][lrow] = b0.y; Bs[lk + 2][lrow] = b0.z; Bs[lk + 3][lrow] = b0.w;
    Bs[lk + 0][lrow + 32] = b1.x; Bs[lk + 1][lrow + 32] = b1.y; Bs[lk + 2][lrow + 32] = b1.z; Bs[lk + 3][lrow + 32] = b1.w;
    __syncthreads();
#pragma unroll
    for (int k = 0; k < 32; ++k) {
      float4 av = *(const float4*)&As[k][ty << 2];
      float4 bv = *(const float4*)&Bs[k][tx << 2];
      float aa[4] = {av.x, av.y, av.z, av.w};
      float bb[4] = {bv.x, bv.y, bv.z, bv.w};
#pragma unroll
      for (int r = 0; r < 4; ++r)
#pragma unroll
        for (int c = 0; c < 4; ++c) acc[r][c] = fmaf(aa[r], bb[c], acc[r][c]);
    }
  }
#pragma unroll
  for (int r = 0; r < 4; ++r) {
    int i = i0 + (ty << 2) + r;
    float ri = r2[i];
    unsigned short oo[4];
#pragma unroll
    for (int c = 0; c < 4; ++c) {
      int j = j0 + (tx << 2) + c;
      float d2 = ri + t2[j] - 2.0f * acc[r][c];
      float dd = sqrtf(fmaxf(d2, 0.f));
      unsigned bits = __float_as_uint(dd);
      oo[c] = (unsigned short)((bits + 0x7FFFu + ((bits >> 16) & 1u)) >> 16);
    }
    ushort4 ov; ov.x = oo[0]; ov.y = oo[1]; ov.z = oo[2]; ov.w = oo[3];
    *reinterpret_cast<ushort4*>(dist + (size_t)i * SS + j0 + (tx << 2)) = ov;
  }
}

// ---------------- banded wavefront DP, R=8 rows/lane, K=8 cols/step ----------------
// Band b = rows [512b, 512b+512); lane l owns rows 512b+8l .. +8l+7.
// Super-step sigma: lane l computes chunk c = sigma - l (cols [8c, 8c+8)).
// Handoff: bottom row of lane's tile -> lane+1 via shfl_up at step end.
// Lane 0 of band b>0 takes its up-row from brow[b-1] (LDS-cached per 64-col group).

#define STEP(G, S, DQ, DQN)                                                    \
  {                                                                            \
    const int sigma = 8 * (G) + (S);                                           \
    const int c = sigma - lane;                                                \
    int cp = c + 1;                                                            \
    cp = cp < 0 ? 0 : cp;                                                      \
    cp = cp >= NCHUNK ? NCHUNK - 1 : cp;                                       \
    const size_t cb = (size_t)cp * KK;                                         \
    _Pragma("unroll")                                                          \
    for (int r = 0; r < RR; ++r)                                               \
      DQN[r] = *(const uint4*)(dptr + (size_t)r * SS + cb);                    \
    float d[RR][KK];                                                           \
    _Pragma("unroll")                                                          \
    for (int r = 0; r < RR; ++r) {                                             \
      unsigned w0 = DQ[r].x, w1 = DQ[r].y, w2 = DQ[r].z, w3 = DQ[r].w;         \
      d[r][0] = __uint_as_float(w0 << 16);                                     \
      d[r][1] = __uint_as_float(w0 & 0xffff0000u);                             \
      d[r][2] = __uint_as_float(w1 << 16);                                     \
      d[r][3] = __uint_as_float(w1 & 0xffff0000u);                             \
      d[r][4] = __uint_as_float(w2 << 16);                                     \
      d[r][5] = __uint_as_float(w2 & 0xffff0000u);                             \
      d[r][6] = __uint_as_float(w3 << 16);                                     \
      d[r][7] = __uint_as_float(w3 & 0xffff0000u);                             \
    }                                                                          \
    float bot[KK];                                                             \
    float ul = ul_top;                                                         \
    _Pragma("unroll")                                                          \
    for (int k = 0; k < KK; ++k) {                                             \
      float up = u[k];                                                         \
      float ulr = ul;                                                          \
      _Pragma("unroll")                                                        \
      for (int r = 0; r < RR; ++r) {                                           \
        float diag = left[r];                                                  \
        float nv = d[r][k] + fminf(fminf(up, ulr), left[r]);                   \
        left[r] = nv;                                                          \
        ulr = diag;                                                            \
        up = nv;                                                               \
      }                                                                        \
      bot[k] = left[RR - 1];                                                   \
      ul = u[k];                                                               \
    }                                                                          \
    ul_top = u[KK - 1];                                                        \
    const bool cvalid = (c >= 0) && (c < NCHUNK);                              \
    if (lane == 63 && cvalid && b < NBANDS - 1) {                              \
      float4* bpp = (float4*)(brow + (size_t)b * SS + (size_t)c * KK);         \
      bpp[0] = make_float4(bot[0], bot[1], bot[2], bot[3]);                    \
      bpp[1] = make_float4(bot[4], bot[5], bot[6], bot[7]);                    \
    }                                                                          \
    if (cvalid && c == NCHUNK - 1) ans = bot[KK - 1];                          \
    if (b < NBANDS - 1 && sigma >= 70 && ((sigma - 70) & 7) == 0 &&            \
        (sigma - 63) < NCHUNK) {                                               \
      __threadfence();                                                         \
      if (lane == 63)                                                          \
        __hip_atomic_store(progress + b, ((sigma - 63) >> 3) + 1,              \
                           __ATOMIC_RELEASE, __HIP_MEMORY_SCOPE_AGENT);        \
    }                                                                          \
    _Pragma("unroll")                                                          \
    for (int k = 0; k < KK; ++k) u[k] = __shfl_up(bot[k], 1, 64);              \
    if ((S) < 7 && lane == 0) {                                                \
      const bool act = (b > 0) && ((sigma + 1) < NCHUNK);                      \
      _Pragma("unroll")                                                        \
      for (int k = 0; k < KK; ++k)                                             \
        u[k] = act ? upb[8 * ((S) + 1) + k] : HUGEV;                           \
    }                                                                          \
  }

__global__ __launch_bounds__(64) void dtw_dp(const unsigned short* __restrict__ dist,
                                             float* __restrict__ brow,
                                             int* __restrict__ progress,
                                             float* __restrict__ out) {
  const int b = blockIdx.x;
  const int lane = threadIdx.x;
  __shared__ float upb[64];
  const unsigned short* dptr = dist + (size_t)(b * BH + lane * RR) * SS;

  float left[RR];
#pragma unroll
  for (int r = 0; r < RR; ++r) left[r] = HUGEV;
  float u[KK];
#pragma unroll
  for (int k = 0; k < KK; ++k) u[k] = HUGEV;
  float ul_top = (b == 0 && lane == 0) ? 0.f : HUGEV;
  float ans = 0.f;

  uint4 dqA[RR], dqB[RR];
#pragma unroll
  for (int r = 0; r < RR; ++r) dqA[r] = *(const uint4*)(dptr + (size_t)r * SS);

  for (int g = 0; g < NG; ++g) {
    if (b > 0 && g < (NCHUNK / 8)) {
      while (__hip_atomic_load(progress + (b - 1), __ATOMIC_ACQUIRE,
                               __HIP_MEMORY_SCOPE_AGENT) < g + 1)
        __builtin_amdgcn_s_sleep(2);
      upb[lane] = brow[(size_t)(b - 1) * SS + 64 * g + lane];
    }
    __syncthreads();
    if (lane == 0) {
      const bool act = (b > 0) && (g < (NCHUNK / 8));
#pragma unroll
      for (int k = 0; k < KK; ++k) u[k] = act ? upb[k] : HUGEV;
    }
    STEP(g, 0, dqA, dqB)
    STEP(g, 1, dqB, dqA)
    STEP(g, 2, dqA, dqB)
    STEP(g, 3, dqB, dqA)
    STEP(g, 4, dqA, dqB)
    STEP(g, 5, dqB, dqA)
    STEP(g, 6, dqA, dqB)
    STEP(g, 7, dqB, dqA)
  }
  if (b == NBANDS - 1 && lane == 63) out[0] = ans;
}

extern "C" void kernel_launch(void* const* d_in, const int* in_sizes, int n_in,
                              void* d_out, int out_size, void* d_ws, size_t ws_size,
                              hipStream_t stream) {
  const float* ref = (const float*)d_in[0];
  const float* tgt = (const float*)d_in[1];
  float* out = (float*)d_out;
  char* ws = (char*)d_ws;
  unsigned short* dist = (unsigned short*)ws;
  size_t off = (size_t)TT * SS * 2;
  float* brow = (float*)(ws + off);      off += (size_t)64 * SS * 4;
  int* progress = (int*)(ws + off);      off += 1024;
  float* r2 = (float*)(ws + off);        off += (size_t)TT * 4;
  float* t2 = (float*)(ws + off);

  dtw_init<<<1, 64, 0, stream>>>(progress);
  dtw_norms<<<(TT + SS) / 256, 256, 0, stream>>>(ref, tgt, r2, t2);
  dtw_dist<<<dim3(SS / 64, TT / 64), 256, 0, stream>>>(ref, tgt, r2, t2, dist);
  dtw_dp<<<NBANDS, 64, 0, stream>>>(dist, brow, progress, out);
}

// Round 3
// 742.275 us; speedup vs baseline: 2.1405x; 1.3045x over previous
//
#include <hip/hip_runtime.h>
#include <hip/hip_bf16.h>

#define TT 4096
#define SS 4096
#define DD 128
#define HUGEV 1e30f

#define RR 8                    // rows per lane
#define KK 8                    // cols per super-step
#define BH (64 * RR)            // band height = 512
#define NBANDS (TT / BH)        // 8
#define NCHUNK (SS / KK)        // 512 col-chunks per band
#define NSIG 576                // sigma slots (tc + lane: 0..574, padded)
#define NG 72                   // 72 groups x 8 steps = 576 super-steps

// ---------------- init: zero progress flags (graph replay!) ----------------
__global__ __launch_bounds__(64) void dtw_init(int* __restrict__ progress) {
  progress[threadIdx.x] = 0;
}

// ---------------- row norms ----------------
__global__ __launch_bounds__(256) void dtw_norms(const float* __restrict__ ref,
                                                 const float* __restrict__ tgt,
                                                 float* __restrict__ r2,
                                                 float* __restrict__ t2) {
  int i = blockIdx.x * 256 + threadIdx.x;
  const float* p = (i < TT) ? (ref + (size_t)i * DD) : (tgt + (size_t)(i - TT) * DD);
  float s = 0.f;
#pragma unroll
  for (int k = 0; k < DD; k += 4) {
    float4 v = *(const float4*)(p + k);
    s = fmaf(v.x, v.x, s); s = fmaf(v.y, v.y, s);
    s = fmaf(v.z, v.z, s); s = fmaf(v.w, v.w, s);
  }
  if (i < TT) r2[i] = s; else t2[i - TT] = s;
}

// ---------------- dist -> skewed tile layout, bf16 ----------------
// Element (i,j): b=i>>9, lane=(i>>3)&63, r=i&7, tc=j>>3, k=j&7, sigma=tc+lane.
// ushort index = ((b*NSIG + sigma)*64 + lane)*64 + r*8 + k.
// One lane-tile (8x8 bf16 = 128B) is contiguous = one cache line for the DP.
__global__ __launch_bounds__(256) void dtw_dist(const float* __restrict__ ref,
                                                const float* __restrict__ tgt,
                                                const float* __restrict__ r2,
                                                const float* __restrict__ t2,
                                                unsigned short* __restrict__ dist) {
  __shared__ float As[32][68];
  __shared__ float Bs[32][68];
  const int tid = threadIdx.x;
  const int tx = tid & 15, ty = tid >> 4;
  const int i0 = blockIdx.y * 64, j0 = blockIdx.x * 64;
  const int lrow = tid >> 3;
  const int lk = (tid & 7) << 2;
  const float* ap = ref + (size_t)(i0 + lrow) * DD + lk;
  const float* bp = tgt + (size_t)(j0 + lrow) * DD + lk;
  float acc[4][4] = {};
  for (int k0 = 0; k0 < DD; k0 += 32) {
    float4 a0 = *(const float4*)(ap + k0);
    float4 a1 = *(const float4*)(ap + k0 + 32 * DD);
    float4 b0 = *(const float4*)(bp + k0);
    float4 b1 = *(const float4*)(bp + k0 + 32 * DD);
    __syncthreads();
    As[lk + 0][lrow] = a0.x; As[lk + 1][lrow] = a0.y; As[lk + 2][lrow] = a0.z; As[lk + 3][lrow] = a0.w;
    As[lk + 0][lrow + 32] = a1.x; As[lk + 1][lrow + 32] = a1.y; As[lk + 2][lrow + 32] = a1.z; As[lk + 3][lrow + 32] = a1.w;
    Bs[lk + 0][lrow] = b0.x; Bs[lk + 1][lrow] = b0.y; Bs[lk + 2][lrow] = b0.z; Bs[lk + 3][lrow] = b0.w;
    Bs[lk + 0][lrow + 32] = b1.x; Bs[lk + 1][lrow + 32] = b1.y; Bs[lk + 2][lrow + 32] = b1.z; Bs[lk + 3][lrow + 32] = b1.w;
    __syncthreads();
#pragma unroll
    for (int k = 0; k < 32; ++k) {
      float4 av = *(const float4*)&As[k][ty << 2];
      float4 bv = *(const float4*)&Bs[k][tx << 2];
      float aa[4] = {av.x, av.y, av.z, av.w};
      float bb[4] = {bv.x, bv.y, bv.z, bv.w};
#pragma unroll
      for (int r = 0; r < 4; ++r)
#pragma unroll
        for (int c = 0; c < 4; ++c) acc[r][c] = fmaf(aa[r], bb[c], acc[r][c]);
    }
  }
#pragma unroll
  for (int r = 0; r < 4; ++r) {
    const int i = i0 + (ty << 2) + r;
    const float ri = r2[i];
    unsigned short oo[4];
#pragma unroll
    for (int c = 0; c < 4; ++c) {
      int j = j0 + (tx << 2) + c;
      float d2 = ri + t2[j] - 2.0f * acc[r][c];
      float dd = sqrtf(fmaxf(d2, 0.f));
      unsigned bits = __float_as_uint(dd);
      oo[c] = (unsigned short)((bits + 0x7FFFu + ((bits >> 16) & 1u)) >> 16);
    }
    ushort4 ov; ov.x = oo[0]; ov.y = oo[1]; ov.z = oo[2]; ov.w = oo[3];
    const int jj = j0 + (tx << 2);
    const int bnd = i >> 9, ln = (i >> 3) & 63, rr = i & 7;
    const int tc = jj >> 3, kk0 = jj & 7;
    const size_t idx =
        ((((size_t)bnd * NSIG + tc + ln) << 6) + (size_t)ln) * 64 + rr * 8 + kk0;
    *reinterpret_cast<ushort4*>(dist + idx) = ov;
  }
}

// ---------------- banded wavefront DP, R=8 rows/lane, K=8 cols/step ----------------
// Band b = rows [512b, 512b+512); lane l owns rows 512b+8l..+8l+7.
// Super-step sigma: lane l computes tile-col c = sigma - l (cols [8c,8c+8)).
// Lane's dist tile = contiguous 128B at tb[(sigma*64+lane)*64].
// STEP consumes BUF (tile sigma) and prefetches tile sigma+2 into BUF.

#define STEP(G, S, BUF)                                                        \
  {                                                                            \
    const int sigma = 8 * (G) + (S);                                           \
    const int c = sigma - lane;                                                \
    float bot[KK];                                                             \
    float unew[KK];                                                            \
    float ul = ul_top;                                                         \
    _Pragma("unroll")                                                          \
    for (int k = 0; k < KK; ++k) {                                             \
      float up = u[k];                                                         \
      float ulr = ul;                                                          \
      _Pragma("unroll")                                                        \
      for (int r = 0; r < RR; ++r) {                                           \
        unsigned w = ((k >> 1) == 0) ? BUF[r].x                                \
                   : ((k >> 1) == 1) ? BUF[r].y                                \
                   : ((k >> 1) == 2) ? BUF[r].z : BUF[r].w;                    \
        float dv = (k & 1) ? __uint_as_float(w & 0xffff0000u)                  \
                           : __uint_as_float(w << 16);                         \
        float diag = left[r];                                                  \
        float nv = dv + fminf(fminf(up, ulr), left[r]);                        \
        left[r] = nv;                                                          \
        ulr = diag;                                                            \
        up = nv;                                                               \
      }                                                                        \
      bot[k] = up;                                                             \
      unew[k] = __shfl_up(up, 1, 64);                                          \
      ul = u[k];                                                               \
    }                                                                          \
    ul_top = u[KK - 1];                                                        \
    {                                                                          \
      int sp = sigma + 2; sp = sp > (NSIG - 1) ? (NSIG - 1) : sp;              \
      const unsigned short* tp = tb + (((size_t)sp << 6) + lane) * 64;         \
      _Pragma("unroll")                                                        \
      for (int q = 0; q < RR; ++q) BUF[q] = *(const uint4*)(tp + q * 8);       \
    }                                                                          \
    const bool cvalid = (c >= 0) && (c < NCHUNK);                              \
    if (lane == 63 && cvalid && b < NBANDS - 1) {                              \
      float4* bpp = (float4*)(brow + (size_t)b * SS + (size_t)c * KK);         \
      bpp[0] = make_float4(bot[0], bot[1], bot[2], bot[3]);                    \
      bpp[1] = make_float4(bot[4], bot[5], bot[6], bot[7]);                    \
    }                                                                          \
    if (cvalid && c == NCHUNK - 1) ans = bot[KK - 1];                          \
    if (b < NBANDS - 1 && sigma >= 70 && ((sigma - 70) & 7) == 0 &&            \
        (sigma - 63) < NCHUNK) {                                               \
      if (lane == 63)                                                          \
        __hip_atomic_store(progress + b, ((sigma - 63) >> 3) + 1,              \
                           __ATOMIC_RELEASE, __HIP_MEMORY_SCOPE_AGENT);        \
    }                                                                          \
    if ((S) < 7 && lane == 0) {                                                \
      const bool act = (b > 0) && ((sigma + 1) < NCHUNK);                      \
      _Pragma("unroll")                                                        \
      for (int k = 0; k < KK; ++k)                                             \
        unew[k] = act ? upb[8 * ((S) + 1) + k] : HUGEV;                        \
    }                                                                          \
    _Pragma("unroll")                                                          \
    for (int k = 0; k < KK; ++k) u[k] = unew[k];                               \
  }

__global__ __launch_bounds__(64) void dtw_dp(const unsigned short* __restrict__ dist,
                                             float* __restrict__ brow,
                                             int* __restrict__ progress,
                                             float* __restrict__ out) {
  const int b = blockIdx.x;
  const int lane = threadIdx.x;
  __shared__ float upb[64];
  const unsigned short* tb = dist + (size_t)b * NSIG * 64 * 64;

  float left[RR];
#pragma unroll
  for (int r = 0; r < RR; ++r) left[r] = HUGEV;
  float u[KK];
#pragma unroll
  for (int k = 0; k < KK; ++k) u[k] = HUGEV;
  float ul_top = (b == 0 && lane == 0) ? 0.f : HUGEV;
  float ans = 0.f;

  uint4 dqA[RR], dqB[RR];
  {
    const unsigned short* tp0 = tb + (size_t)lane * 64;
    const unsigned short* tp1 = tb + ((size_t)64 + lane) * 64;
#pragma unroll
    for (int q = 0; q < RR; ++q) {
      dqA[q] = *(const uint4*)(tp0 + q * 8);
      dqB[q] = *(const uint4*)(tp1 + q * 8);
    }
  }

  for (int g = 0; g < NG; ++g) {
    if (b > 0 && g < (NCHUNK / 8)) {
      while (__hip_atomic_load(progress + (b - 1), __ATOMIC_ACQUIRE,
                               __HIP_MEMORY_SCOPE_AGENT) < g + 1)
        __builtin_amdgcn_s_sleep(2);
      upb[lane] = brow[(size_t)(b - 1) * SS + 64 * g + lane];
    }
    if (lane == 0) {
      const bool act = (b > 0) && (g < (NCHUNK / 8));
#pragma unroll
      for (int k = 0; k < KK; ++k) u[k] = act ? upb[k] : HUGEV;
    }
    STEP(g, 0, dqA)
    STEP(g, 1, dqB)
    STEP(g, 2, dqA)
    STEP(g, 3, dqB)
    STEP(g, 4, dqA)
    STEP(g, 5, dqB)
    STEP(g, 6, dqA)
    STEP(g, 7, dqB)
  }
  if (b == NBANDS - 1 && lane == 63) out[0] = ans;
}

extern "C" void kernel_launch(void* const* d_in, const int* in_sizes, int n_in,
                              void* d_out, int out_size, void* d_ws, size_t ws_size,
                              hipStream_t stream) {
  const float* ref = (const float*)d_in[0];
  const float* tgt = (const float*)d_in[1];
  float* out = (float*)d_out;
  char* ws = (char*)d_ws;
  unsigned short* dist = (unsigned short*)ws;       // skewed tiles: 37,748,736 B
  size_t off = (size_t)NBANDS * NSIG * 64 * 64 * 2;
  float* brow = (float*)(ws + off);      off += (size_t)64 * SS * 4;
  int* progress = (int*)(ws + off);      off += 1024;
  float* r2 = (float*)(ws + off);        off += (size_t)TT * 4;
  float* t2 = (float*)(ws + off);

  dtw_init<<<1, 64, 0, stream>>>(progress);
  dtw_norms<<<(TT + SS) / 256, 256, 0, stream>>>(ref, tgt, r2, t2);
  dtw_dist<<<dim3(SS / 64, TT / 64), 256, 0, stream>>>(ref, tgt, r2, t2, dist);
  dtw_dp<<<NBANDS, 64, 0, stream>>>(dist, brow, progress, out);
}